// Round 7
// baseline (780.451 us; speedup 1.0000x reference)
//
#include <hip/hip_runtime.h>
#include <math.h>

// Problem constants
constexpr int Nn  = 100000;  // nodes
constexpr int Ee  = 800000;  // edges
constexpr int Bb  = 4096;    // graphs
constexpr int Vv  = 103;     // vocab
constexpr int DIN = 200;     // embedding dim
constexpr int Hh  = 256;     // hidden
constexpr int KV  = 128;     // padded vocab dim for hist GEMM

constexpr int SCHUNK = 1024;
constexpr int NSCAN  = (Nn + SCHUNK - 1)/SCHUNK;   // 98 blocks

using short8 = __attribute__((ext_vector_type(8))) short;
using f32x4  = __attribute__((ext_vector_type(4))) float;

__device__ __forceinline__ float sigf(float x){ return 1.f/(1.f+expf(-x)); }

__device__ __forceinline__ unsigned short f2bf(float f){
  unsigned int u = __float_as_uint(f);
  u += 0x7FFFu + ((u >> 16) & 1u);
  return (unsigned short)(u >> 16);
}
__device__ __forceinline__ float bf2f(unsigned int u){
  return __uint_as_float((u & 0xFFFFu) << 16);
}

// ---------------- small utility kernels ----------------
__global__ void k_transpose(const float* __restrict__ in, float* __restrict__ out, int R, int C){
  int idx = blockIdx.x*256 + threadIdx.x;
  if (idx >= R*C) return;
  int r = idx / C, c = idx % C;
  out[(size_t)c*R + r] = in[(size_t)r*C + c];
}

__global__ void k_transpose_b(const float* __restrict__ in, unsigned short* __restrict__ out, int R, int C){
  int idx = blockIdx.x*256 + threadIdx.x;
  if (idx >= R*C) return;
  int r = idx / C, c = idx % C;
  out[(size_t)c*R + r] = f2bf(in[(size_t)r*C + c]);
}

__global__ void k_castb(const float* __restrict__ in, unsigned short* __restrict__ out, int n){
  int i = blockIdx.x*256 + threadIdx.x;
  if (i < n) out[i] = f2bf(in[i]);
}

// WG0 fp32 [103][256] -> bf16 [256][128] (padded, transposed)
__global__ void k_wg0t(const float* __restrict__ WG0, unsigned short* __restrict__ WG0tb){
  int i = blockIdx.x*256 + threadIdx.x;
  if (i >= Hh*KV) return;
  int n = i >> 7, k = i & (KV-1);
  float v = (k < Vv) ? WG0[(size_t)k*Hh + n] : 0.f;
  WG0tb[i] = f2bf(v);
}

// pack [Wih | Whh] -> bf16 [1024][768]
__global__ void k_packW(const float* __restrict__ Wih, const float* __restrict__ Whh,
                        unsigned short* __restrict__ Wp){
  int i = blockIdx.x*256 + threadIdx.x;
  if (i >= 4*Hh*3*Hh) return;
  int g = i / (3*Hh), j = i % (3*Hh);
  float v = (j < 2*Hh) ? Wih[(size_t)g*2*Hh + j] : Whh[(size_t)g*Hh + (j - 2*Hh)];
  Wp[i] = f2bf(v);
}

__global__ void k_count(const int* __restrict__ dst, int* __restrict__ counts){
  int e = blockIdx.x*256 + threadIdx.x;
  if (e < Ee) atomicAdd(&counts[dst[e]], 1);
}

__global__ void k_dinv(const int* __restrict__ counts, float* __restrict__ dinv){
  int n = blockIdx.x*256 + threadIdx.x;
  if (n < Nn) dinv[n] = rsqrtf((float)(counts[n] + 1));
}

// ---------------- hierarchical scan (3 phases) ----------------
__global__ void k_scan1(const int* __restrict__ counts, int* __restrict__ partial){
  __shared__ int red[256];
  int t = threadIdx.x;
  int base = blockIdx.x*SCHUNK + t*4;
  int s = 0;
  if (base + 3 < Nn){ int4 v = *reinterpret_cast<const int4*>(counts + base); s = v.x+v.y+v.z+v.w; }
  else { for (int i=0;i<4;++i) if (base+i<Nn) s += counts[base+i]; }
  red[t] = s; __syncthreads();
  for (int st=128; st>0; st>>=1){ if (t<st) red[t]+=red[t+st]; __syncthreads(); }
  if (t==0) partial[blockIdx.x] = red[0];
}

__global__ void k_scan2(int* __restrict__ partial, int n){
  __shared__ int buf[128];
  int t = threadIdx.x;
  int v = (t < n) ? partial[t] : 0;
  buf[t] = v; __syncthreads();
  for (int off=1; off<128; off<<=1){
    int tv = (t>=off) ? buf[t-off] : 0;
    __syncthreads();
    buf[t] += tv;
    __syncthreads();
  }
  if (t < n) partial[t] = buf[t] - v;
}

__global__ void k_scan3(const int* __restrict__ counts, const int* __restrict__ partial,
                        int* __restrict__ offs){
  __shared__ int red[256];
  int t = threadIdx.x;
  int base = blockIdx.x*SCHUNK + t*4;
  int c0=0,c1=0,c2=0,c3=0;
  if (base + 3 < Nn){ int4 v = *reinterpret_cast<const int4*>(counts + base); c0=v.x;c1=v.y;c2=v.z;c3=v.w; }
  else { if (base<Nn) c0=counts[base]; if (base+1<Nn) c1=counts[base+1];
         if (base+2<Nn) c2=counts[base+2]; if (base+3<Nn) c3=counts[base+3]; }
  int s = c0+c1+c2+c3;
  red[t] = s; __syncthreads();
  for (int off=1; off<256; off<<=1){
    int tv = (t>=off) ? red[t-off] : 0;
    __syncthreads();
    red[t] += tv;
    __syncthreads();
  }
  int run = partial[blockIdx.x] + red[t] - s;
  if (base   < Nn) offs[base]   = run; run += c0;
  if (base+1 < Nn) offs[base+1] = run; run += c1;
  if (base+2 < Nn) offs[base+2] = run; run += c2;
  if (base+3 < Nn) offs[base+3] = run; run += c3;
  if (blockIdx.x == gridDim.x-1 && t == 255) offs[Nn] = partial[blockIdx.x] + red[255];
}

__global__ void k_copyi(const int* __restrict__ a, int* __restrict__ b, int n){
  int i = blockIdx.x*256 + threadIdx.x;
  if (i < n) b[i] = a[i];
}

__global__ void k_fill(const int* __restrict__ ei, const float* __restrict__ dinv,
                       int* __restrict__ fptr, int* __restrict__ srcs, float* __restrict__ norms){
  int e = blockIdx.x*256 + threadIdx.x;
  if (e >= Ee) return;
  int s = ei[e], d = ei[Ee + e];
  int pos = atomicAdd(&fptr[d], 1);
  srcs[pos]  = s;
  norms[pos] = dinv[s]*dinv[d];
}

__global__ void k_boffs(const int* __restrict__ batch, int* __restrict__ boffs){
  int b = blockIdx.x*256 + threadIdx.x;
  if (b > Bb) return;
  int lo = 0, hi = Nn;
  while (lo < hi){ int mid = (lo+hi)>>1; if (batch[mid] < b) lo = mid+1; else hi = mid; }
  boffs[b] = lo;
}

// ---------------- layer 0: vocab histogram (wave per node) ----------------
__global__ void k_hist(const int* __restrict__ sto_x, const int* __restrict__ offs,
                       const int* __restrict__ srcs, const float* __restrict__ norms,
                       const float* __restrict__ dinv, unsigned short* __restrict__ Vb){
  __shared__ float hist[4][KV];
  int wid = threadIdx.x >> 6, lane = threadIdx.x & 63;
  int n = blockIdx.x*4 + wid;
  hist[wid][lane] = 0.f; hist[wid][lane+64] = 0.f;
  __syncthreads();
  int s = offs[n], e = offs[n+1];
  for (int k = s + lane; k < e; k += 64){
    int r2 = sto_x[srcs[k]]; r2 = (r2 == 0) ? (Vv-1) : r2-1;
    atomicAdd(&hist[wid][r2], norms[k]);
  }
  if (lane == 0){
    int r0 = sto_x[n]; r0 = (r0 == 0) ? (Vv-1) : r0-1;
    float dn = dinv[n];
    atomicAdd(&hist[wid][r0], dn*dn);
  }
  __syncthreads();
  unsigned int p = ((unsigned int)f2bf(hist[wid][2*lane+1]) << 16) | f2bf(hist[wid][2*lane]);
  ((unsigned int*)Vb)[(size_t)n*(KV/2) + lane] = p;
}

// ---------------- GCN aggregate (wave per node, uint2 lanes, 4-edge unroll) ----------------
__global__ void k_agg(const unsigned short* __restrict__ Xb, const int* __restrict__ offs,
                      const int* __restrict__ srcs, const float* __restrict__ norms,
                      const float* __restrict__ dinv, unsigned short* __restrict__ T){
  int wid = threadIdx.x >> 6, lane = threadIdx.x & 63;
  int n = blockIdx.x*4 + wid;
  const uint2* Xv = (const uint2*)Xb;
  uint2 v = Xv[(size_t)n*64 + lane];
  float dn = dinv[n]; float s2 = dn*dn;
  float a0 = bf2f(v.x)*s2, a1 = bf2f(v.x>>16)*s2;
  float a2 = bf2f(v.y)*s2, a3 = bf2f(v.y>>16)*s2;
  int s = offs[n], e = offs[n+1];
  int k = s;
  for (; k + 3 < e; k += 4){
    int s0 = srcs[k], s1 = srcs[k+1], s2i = srcs[k+2], s3 = srcs[k+3];
    float n0 = norms[k], n1 = norms[k+1], n2 = norms[k+2], n3 = norms[k+3];
    uint2 g0 = Xv[(size_t)s0*64 + lane];
    uint2 g1 = Xv[(size_t)s1*64 + lane];
    uint2 g2 = Xv[(size_t)s2i*64 + lane];
    uint2 g3 = Xv[(size_t)s3*64 + lane];
    a0 += bf2f(g0.x)*n0; a1 += bf2f(g0.x>>16)*n0; a2 += bf2f(g0.y)*n0; a3 += bf2f(g0.y>>16)*n0;
    a0 += bf2f(g1.x)*n1; a1 += bf2f(g1.x>>16)*n1; a2 += bf2f(g1.y)*n1; a3 += bf2f(g1.y>>16)*n1;
    a0 += bf2f(g2.x)*n2; a1 += bf2f(g2.x>>16)*n2; a2 += bf2f(g2.y)*n2; a3 += bf2f(g2.y>>16)*n2;
    a0 += bf2f(g3.x)*n3; a1 += bf2f(g3.x>>16)*n3; a2 += bf2f(g3.y)*n3; a3 += bf2f(g3.y>>16)*n3;
  }
  for (; k < e; ++k){
    uint2 g0 = Xv[(size_t)srcs[k]*64 + lane];
    float n0 = norms[k];
    a0 += bf2f(g0.x)*n0; a1 += bf2f(g0.x>>16)*n0;
    a2 += bf2f(g0.y)*n0; a3 += bf2f(g0.y>>16)*n0;
  }
  uint2 o;
  o.x = (unsigned int)f2bf(a0) | ((unsigned int)f2bf(a1) << 16);
  o.y = (unsigned int)f2bf(a2) | ((unsigned int)f2bf(a3) << 16);
  ((uint2*)T)[(size_t)n*64 + lane] = o;
}

// ---------------- register-resident bf16 MFMA GEMM (no LDS, no barriers) ----------------
// Block = 4 waves; block tile 64 rows x 256 cols; wave tile 64x64 (4x4 16x16 frags).
// A [M][lda] bf16, Bt [Nc][K] bf16 (L2-resident weights; per-(col,kstep) reads consume
// exactly one 64B line across the 4 kh-groups -> zero over-fetch).
// out = epi(A@Bt^T + bias + addf) ; epi: *rowscale, relu; writes Cf (fp32) and/or Cb (bf16).
// Requires: Nc % 256 == 0, K % 32 == 0.
__global__ __launch_bounds__(256) void k_gemm_reg(
    const unsigned short* __restrict__ A, int lda,
    const unsigned short* __restrict__ Bt,
    const float* __restrict__ bias, const float* __restrict__ rowscale,
    const float* __restrict__ addf,
    float* __restrict__ Cf, unsigned short* __restrict__ Cb,
    int M, int K, int Nc, int relu)
{
  int tid = threadIdx.x;
  int w = tid >> 6, lane = tid & 63;
  int l16 = lane & 15, kh = lane >> 4;
  int rbase = blockIdx.y*64;
  int cbase = blockIdx.x*256 + w*64;

  f32x4 acc[4][4] = {};
  const uint4 uz = make_uint4(0,0,0,0);
  int nk = K >> 5;

  const unsigned short* ap[4];
  const unsigned short* bp[4];
  bool av[4];
  #pragma unroll
  for (int f = 0; f < 4; ++f){
    int r = rbase + f*16 + l16;
    av[f] = r < M;
    ap[f] = A + (size_t)(av[f] ? r : 0)*lda + kh*8;
    int c = cbase + f*16 + l16;
    bp[f] = Bt + (size_t)c*K + kh*8;
  }

  uint4 ac[4], bc[4];
  #pragma unroll
  for (int f = 0; f < 4; ++f){
    ac[f] = av[f] ? *reinterpret_cast<const uint4*>(ap[f]) : uz;
    bc[f] = *reinterpret_cast<const uint4*>(bp[f]);
  }

  for (int kk = 0; kk < nk; ++kk){
    uint4 an[4] = {uz,uz,uz,uz}, bn[4] = {uz,uz,uz,uz};
    if (kk + 1 < nk){
      int ko = (kk+1)*32;
      #pragma unroll
      for (int f = 0; f < 4; ++f){
        if (av[f]) an[f] = *reinterpret_cast<const uint4*>(ap[f] + ko);
        bn[f] = *reinterpret_cast<const uint4*>(bp[f] + ko);
      }
    }
    short8 as[4], bs[4];
    #pragma unroll
    for (int f = 0; f < 4; ++f){
      as[f] = *reinterpret_cast<short8*>(&ac[f]);
      bs[f] = *reinterpret_cast<short8*>(&bc[f]);
    }
    #pragma unroll
    for (int m = 0; m < 4; ++m)
      #pragma unroll
      for (int n2 = 0; n2 < 4; ++n2)
        acc[m][n2] = __builtin_amdgcn_mfma_f32_16x16x32_bf16(as[m], bs[n2], acc[m][n2], 0, 0, 0);
    #pragma unroll
    for (int f = 0; f < 4; ++f){ ac[f] = an[f]; bc[f] = bn[f]; }
  }

  #pragma unroll
  for (int n2 = 0; n2 < 4; ++n2){
    int col = cbase + n2*16 + l16;
    float bv = bias ? bias[col] : 0.f;
    #pragma unroll
    for (int m = 0; m < 4; ++m){
      #pragma unroll
      for (int i = 0; i < 4; ++i){
        int row = rbase + m*16 + kh*4 + i;
        if (row >= M) continue;
        float v = acc[m][n2][i] + bv;
        if (addf) v += addf[(size_t)row*Nc + col];
        if (rowscale) v *= rowscale[row];
        if (relu) v = fmaxf(v, 0.f);
        if (Cf) Cf[(size_t)row*Nc + col] = v;
        if (Cb) Cb[(size_t)row*Nc + col] = f2bf(v);
      }
    }
  }
}

// ---------------- tiled fp32 NT GEMM (small GEMMs) ----------------
__global__ __launch_bounds__(256) void k_gemm_nt(
    const float* __restrict__ A, const float* __restrict__ Bt,
    const float* __restrict__ bias, const float* __restrict__ Dadd,
    float* __restrict__ C, int M, int K, int Nc, int accum, int act)
{
  __shared__ float As[64][20];
  __shared__ float Bs[64][20];
  int tid = threadIdx.x;
  int rbase = blockIdx.y*64, cbase = blockIdx.x*64;
  int ty = tid>>4, tx = tid&15;
  int lr = tid>>2, lq = tid&3;
  float acc[4][4] = {};
  for (int k0 = 0; k0 < K; k0 += 16){
    float4 av = make_float4(0,0,0,0), bv = make_float4(0,0,0,0);
    int kk = k0 + lq*4;
    int ar = rbase + lr;
    if (ar < M && kk < K){
      if (kk + 3 < K) av = *reinterpret_cast<const float4*>(A + (size_t)ar*K + kk);
      else { float t0[4] = {0,0,0,0}; for (int i=0; i<4 && kk+i<K; ++i) t0[i] = A[(size_t)ar*K + kk + i];
             av = make_float4(t0[0],t0[1],t0[2],t0[3]); }
    }
    int br = cbase + lr;
    if (br < Nc && kk < K){
      if (kk + 3 < K) bv = *reinterpret_cast<const float4*>(Bt + (size_t)br*K + kk);
      else { float t0[4] = {0,0,0,0}; for (int i=0; i<4 && kk+i<K; ++i) t0[i] = Bt[(size_t)br*K + kk + i];
             bv = make_float4(t0[0],t0[1],t0[2],t0[3]); }
    }
    __syncthreads();
    *reinterpret_cast<float4*>(&As[lr][lq*4]) = av;
    *reinterpret_cast<float4*>(&Bs[lr][lq*4]) = bv;
    __syncthreads();
    #pragma unroll
    for (int kc = 0; kc < 16; kc += 4){
      float4 a4[4], b4[4];
      #pragma unroll
      for (int i=0;i<4;++i) a4[i] = *reinterpret_cast<float4*>(&As[ty*4+i][kc]);
      #pragma unroll
      for (int j=0;j<4;++j) b4[j] = *reinterpret_cast<float4*>(&Bs[tx*4+j][kc]);
      #pragma unroll
      for (int i=0;i<4;++i)
        #pragma unroll
        for (int j=0;j<4;++j)
          acc[i][j] += a4[i].x*b4[j].x + a4[i].y*b4[j].y + a4[i].z*b4[j].z + a4[i].w*b4[j].w;
    }
  }
  #pragma unroll
  for (int i=0;i<4;++i){
    int r = rbase + ty*4 + i;
    if (r >= M) continue;
    #pragma unroll
    for (int j=0;j<4;++j){
      int cc = cbase + tx*4 + j;
      if (cc >= Nc) continue;
      float v = acc[i][j];
      if (accum) v += C[(size_t)r*Nc + cc];
      if (bias)  v += bias[cc];
      if (Dadd)  v += Dadd[(size_t)r*Nc + cc];
      if (act == 1) v = (v > 0.f) ? v : 0.01f*v;
      C[(size_t)r*Nc + cc] = v;
    }
  }
}

// ---------------- pooling / LSTM / head ----------------
__global__ void k_bsum(const float* __restrict__ bih, const float* __restrict__ bhh,
                       float* __restrict__ bsum){
  int g = blockIdx.x*256 + threadIdx.x;
  if (g < 4*Hh) bsum[g] = bih[g] + bhh[g];
}

__global__ void k_lstm(const float* __restrict__ gates, float* __restrict__ cbuf,
                       float* __restrict__ hbuf, unsigned short* __restrict__ qh){
  int idx = blockIdx.x*256 + threadIdx.x;
  if (idx >= Bb*Hh) return;
  int b = idx >> 8, ch = idx & 255;
  const float* g = gates + (size_t)b*4*Hh;
  float ig = sigf(g[ch]);
  float fg = sigf(g[Hh + ch]);
  float gg = tanhf(g[2*Hh + ch]);
  float og = sigf(g[3*Hh + ch]);
  float cn = fg*cbuf[idx] + ig*gg;
  float hn = og*tanhf(cn);
  cbuf[idx] = cn; hbuf[idx] = hn;
  unsigned short hb = f2bf(hn);
  qh[(size_t)b*3*Hh + ch] = hb;
  qh[(size_t)b*3*Hh + 2*Hh + ch] = hb;
}

// fused Set2Set pool: wave per graph, online softmax + optional plain-sum (sto)
__global__ void k_pool(const unsigned short* __restrict__ wxb,
                       const float* __restrict__ hbuf,
                       const int* __restrict__ boffs,
                       unsigned short* __restrict__ qh,
                       float* __restrict__ sto, int do_sto){
  int wid = threadIdx.x >> 6, lane = threadIdx.x & 63;
  int g = blockIdx.x*4 + wid;
  if (g >= Bb) return;
  const uint2* Xv = (const uint2*)wxb;
  float4 hv = ((const float4*)hbuf)[(size_t)g*64 + lane];
  int s = boffs[g], e = boffs[g+1];
  float m = -INFINITY, ssum = 0.f;
  float a0=0.f,a1=0.f,a2=0.f,a3=0.f;
  float t0=0.f,t1=0.f,t2=0.f,t3=0.f;
  for (int n = s; n < e; ++n){
    uint2 v = Xv[(size_t)n*64 + lane];
    float x0=bf2f(v.x), x1=bf2f(v.x>>16), x2=bf2f(v.y), x3=bf2f(v.y>>16);
    if (do_sto){ t0+=x0; t1+=x1; t2+=x2; t3+=x3; }
    float d = x0*hv.x + x1*hv.y + x2*hv.z + x3*hv.w;
    #pragma unroll
    for (int mask=32; mask; mask>>=1) d += __shfl_xor(d, mask, 64);
    if (d > m){
      float sc = expf(m - d);
      ssum = ssum*sc + 1.f;
      a0 = a0*sc + x0; a1 = a1*sc + x1; a2 = a2*sc + x2; a3 = a3*sc + x3;
      m = d;
    } else {
      float p = expf(d - m);
      ssum += p;
      a0 += p*x0; a1 += p*x1; a2 += p*x2; a3 += p*x3;
    }
  }
  float inv = 1.f/(ssum + 1e-16f);
  uint2 o;
  o.x = (unsigned int)f2bf(a0*inv) | ((unsigned int)f2bf(a1*inv) << 16);
  o.y = (unsigned int)f2bf(a2*inv) | ((unsigned int)f2bf(a3*inv) << 16);
  ((uint2*)(qh + (size_t)g*3*Hh + Hh))[lane] = o;
  if (do_sto) ((float4*)sto)[(size_t)g*64 + lane] = make_float4(t0,t1,t2,t3);
}

__global__ void k_norm(float* __restrict__ mean){
  __shared__ float red[256];
  int b = blockIdx.x, tid = threadIdx.x;
  float v = mean[(size_t)b*Hh + tid];
  red[tid] = v*v; __syncthreads();
  for (int st=128; st>0; st>>=1){ if (tid<st) red[tid] += red[tid+st]; __syncthreads(); }
  float nrm = fmaxf(sqrtf(red[0]), 1e-12f);
  mean[(size_t)b*Hh + tid] = v/nrm;
}

__global__ void k_out(const float* __restrict__ y1, const float* __restrict__ p2W,
                      const float* __restrict__ p2b, float* __restrict__ out){
  __shared__ float red[128];
  int b = blockIdx.x, tid = threadIdx.x;
  float v = y1[(size_t)b*128 + tid]*p2W[tid];
  red[tid] = v; __syncthreads();
  for (int st=64; st>0; st>>=1){ if (tid<st) red[tid] += red[tid+st]; __syncthreads(); }
  if (tid == 0) out[b] = red[0] + p2b[0];
}

// ---------------- launch ----------------
extern "C" void kernel_launch(void* const* d_in, const int* in_sizes, int n_in,
                              void* d_out, int out_size, void* d_ws, size_t ws_size,
                              hipStream_t stream) {
  const float* weight   = (const float*)d_in[0];
  const int*   sto_x    = (const int*)  d_in[1];
  const int*   ei       = (const int*)  d_in[2];
  const float* sto_w    = (const float*)d_in[3];
  const int*   batch    = (const int*)  d_in[4];
  const float* gW0 = (const float*)d_in[5];   const float* gb0 = (const float*)d_in[6];
  const float* gW1 = (const float*)d_in[7];   const float* gb1 = (const float*)d_in[8];
  const float* gW2 = (const float*)d_in[9];   const float* gb2 = (const float*)d_in[10];
  const float* Wih = (const float*)d_in[11];  const float* Whh = (const float*)d_in[12];
  const float* bih = (const float*)d_in[13];  const float* bhh = (const float*)d_in[14];
  const float* mW  = (const float*)d_in[15];  const float* mb  = (const float*)d_in[16];
  const float* p0W = (const float*)d_in[17];  const float* p0b = (const float*)d_in[18];
  const float* p1W = (const float*)d_in[19];  const float* p1b = (const float*)d_in[20];
  const float* p2W = (const float*)d_in[21];  const float* p2b = (const float*)d_in[22];
  float* out = (float*)d_out;

  // workspace carve (256B aligned)
  char* w = (char*)d_ws;
  auto alloc = [&](size_t bytes)->char*{ char* p = w; w += (bytes + 255) & ~size_t(255); return p; };
  unsigned short* Xb = (unsigned short*)alloc((size_t)Nn*Hh*2);
  unsigned short* Tb = (unsigned short*)alloc((size_t)Nn*Hh*2);
  unsigned short* Vb = (unsigned short*)alloc((size_t)Nn*KV*2);
  float* WG0   = (float*)alloc((size_t)Vv*Hh*4);
  unsigned short* WG0tb = (unsigned short*)alloc((size_t)Hh*KV*2);
  float* gW0t  = (float*)alloc((size_t)Hh*DIN*4);
  unsigned short* gW1tb = (unsigned short*)alloc((size_t)Hh*Hh*2);
  unsigned short* gW2tb = (unsigned short*)alloc((size_t)Hh*Hh*2);
  unsigned short* Wpb   = (unsigned short*)alloc((size_t)4*Hh*3*Hh*2);
  unsigned short* mWb   = (unsigned short*)alloc((size_t)Hh*2*Hh*2);
  int*   counts= (int*)  alloc((size_t)Nn*4);
  int*   offs  = (int*)  alloc((size_t)(Nn+1)*4);
  int*   fptr  = (int*)  alloc((size_t)Nn*4);
  int*   spart = (int*)  alloc((size_t)NSCAN*4);
  float* dinv  = (float*)alloc((size_t)Nn*4);
  int*   srcs  = (int*)  alloc((size_t)Ee*4);
  float* norms = (float*)alloc((size_t)Ee*4);
  int*   boffs = (int*)  alloc((size_t)(Bb+1)*4);
  float* sto   = (float*)alloc((size_t)Bb*Hh*4);
  float* hbuf  = (float*)alloc((size_t)Bb*Hh*4);
  float* cbuf  = (float*)alloc((size_t)Bb*Hh*4);
  unsigned short* qh = (unsigned short*)alloc((size_t)Bb*3*Hh*2);
  float* gates = (float*)alloc((size_t)Bb*4*Hh*4);
  float* bsum  = (float*)alloc((size_t)4*Hh*4);
  float* meanb = (float*)alloc((size_t)Bb*Hh*4);
  float* y0    = (float*)alloc((size_t)Bb*128*4);
  float* y1    = (float*)alloc((size_t)Bb*128*4);

  auto gemm = [&](const float* A, const float* Bt, const float* bias, const float* Dadd,
                  float* C, int M, int K, int Nc, int accum, int act){
    dim3 g((Nc+63)/64, (M+63)/64);
    k_gemm_nt<<<g, 256, 0, stream>>>(A, Bt, bias, Dadd, C, M, K, Nc, accum, act);
  };
  auto gemmr = [&](const unsigned short* A, int lda, const unsigned short* Bt,
                   const float* bias, const float* rowscale, const float* addf,
                   float* Cf, unsigned short* Cb, int M, int K, int Nc, int relu){
    dim3 g(Nc/256, (M+63)/64);
    k_gemm_reg<<<g, 256, 0, stream>>>(A, lda, Bt, bias, rowscale, addf, Cf, Cb, M, K, Nc, relu);
  };

  // per-launch state init (deterministic every call)
  hipMemsetAsync(counts, 0, (size_t)Nn*4, stream);
  hipMemsetAsync(cbuf,  0, (size_t)Bb*Hh*4, stream);
  hipMemsetAsync(qh,    0, (size_t)Bb*3*Hh*2, stream);

  // weight prep
  k_transpose<<<(DIN*Hh+255)/256, 256, 0, stream>>>(gW0, gW0t, DIN, Hh);
  k_transpose_b<<<(Hh*Hh+255)/256, 256, 0, stream>>>(gW1, gW1tb, Hh, Hh);
  k_transpose_b<<<(Hh*Hh+255)/256, 256, 0, stream>>>(gW2, gW2tb, Hh, Hh);
  k_packW<<<(4*Hh*3*Hh+255)/256, 256, 0, stream>>>(Wih, Whh, Wpb);
  k_castb<<<(Hh*2*Hh+255)/256, 256, 0, stream>>>(mW, mWb, Hh*2*Hh);

  // graph structure (hierarchical scan)
  k_count<<<(Ee+255)/256, 256, 0, stream>>>(ei + Ee, counts);
  k_dinv<<<(Nn+255)/256, 256, 0, stream>>>(counts, dinv);
  k_scan1<<<NSCAN, 256, 0, stream>>>(counts, spart);
  k_scan2<<<1, 128, 0, stream>>>(spart, NSCAN);
  k_scan3<<<NSCAN, 256, 0, stream>>>(counts, spart, offs);
  k_copyi<<<(Nn+255)/256, 256, 0, stream>>>(offs, fptr, Nn);
  k_fill<<<(Ee+255)/256, 256, 0, stream>>>(ei, dinv, fptr, srcs, norms);
  k_boffs<<<(Bb+256)/256, 256, 0, stream>>>(batch, boffs);

  // layer 0: WG0 = weight@gW0, vocab histogram, register GEMM (bias+relu)
  gemm(weight, gW0t, nullptr, nullptr, WG0, Vv, DIN, Hh, 0, 0);
  k_wg0t<<<(Hh*KV+255)/256, 256, 0, stream>>>(WG0, WG0tb);
  k_hist<<<Nn/4, 256, 0, stream>>>(sto_x, offs, srcs, norms, dinv, Vb);
  gemmr(Vb, KV, WG0tb, gb0, nullptr, nullptr, nullptr, Xb, Nn, KV, Hh, 1);

  // layers 1,2: aggregate-first, register GEMM with fused epilogue
  k_agg<<<Nn/4, 256, 0, stream>>>(Xb, offs, srcs, norms, dinv, Tb);
  gemmr(Tb, Hh, gW1tb, gb1, nullptr, nullptr, nullptr, Xb, Nn, Hh, Hh, 1);
  k_agg<<<Nn/4, 256, 0, stream>>>(Xb, offs, srcs, norms, dinv, Tb);
  gemmr(Tb, Hh, gW2tb, gb2, sto_w, nullptr, nullptr, Xb, Nn, Hh, Hh, 0);  // Xb = wx

  k_bsum<<<(4*Hh+255)/256, 256, 0, stream>>>(bih, bhh, bsum);

  // Set2Set (2 steps): gates GEMM, LSTM, fused pool (sto accumulated at t=0)
  for (int t = 0; t < 2; ++t){
    gemmr(qh, 3*Hh, Wpb, bsum, nullptr, nullptr, gates, nullptr, Bb, 3*Hh, 4*Hh, 0);
    k_lstm<<<(Bb*Hh+255)/256, 256, 0, stream>>>(gates, cbuf, hbuf, qh);
    k_pool<<<Bb/4, 256, 0, stream>>>(Xb, hbuf, boffs, qh, sto, t == 0);
  }

  // head
  gemmr(qh, 3*Hh, mWb, mb, nullptr, sto, meanb, nullptr, Bb, 2*Hh, Hh, 0);
  k_norm<<<Bb, Hh, 0, stream>>>(meanb);
  gemm(meanb, p0W, p0b, nullptr, y0, Bb, Hh, 128, 0, 1);
  gemm(y0, p1W, p1b, nullptr, y1, Bb, 128, 128, 0, 1);
  k_out<<<Bb, 128, 0, stream>>>(y1, p2W, p2b, out);
}

// Round 8
// 592.972 us; speedup vs baseline: 1.3162x; 1.3162x over previous
//
#include <hip/hip_runtime.h>
#include <math.h>

// Problem constants
constexpr int Nn  = 100000;  // nodes
constexpr int Ee  = 800000;  // edges
constexpr int Bb  = 4096;    // graphs
constexpr int Vv  = 103;     // vocab
constexpr int DIN = 200;     // embedding dim
constexpr int Hh  = 256;     // hidden
constexpr int KV  = 128;     // padded vocab dim for hist GEMM

constexpr int SCHUNK = 1024;
constexpr int NSCAN  = (Nn + SCHUNK - 1)/SCHUNK;   // 98 blocks

using short8 = __attribute__((ext_vector_type(8))) short;
using f32x4  = __attribute__((ext_vector_type(4))) float;

__device__ __forceinline__ float sigf(float x){ return 1.f/(1.f+expf(-x)); }

__device__ __forceinline__ unsigned short f2bf(float f){
  unsigned int u = __float_as_uint(f);
  u += 0x7FFFu + ((u >> 16) & 1u);
  return (unsigned short)(u >> 16);
}
__device__ __forceinline__ float bf2f(unsigned int u){
  return __uint_as_float((u & 0xFFFFu) << 16);
}

// ---------------- small utility kernels ----------------
__global__ void k_transpose(const float* __restrict__ in, float* __restrict__ out, int R, int C){
  int idx = blockIdx.x*256 + threadIdx.x;
  if (idx >= R*C) return;
  int r = idx / C, c = idx % C;
  out[(size_t)c*R + r] = in[(size_t)r*C + c];
}

__global__ void k_transpose_b(const float* __restrict__ in, unsigned short* __restrict__ out, int R, int C){
  int idx = blockIdx.x*256 + threadIdx.x;
  if (idx >= R*C) return;
  int r = idx / C, c = idx % C;
  out[(size_t)c*R + r] = f2bf(in[(size_t)r*C + c]);
}

__global__ void k_castb(const float* __restrict__ in, unsigned short* __restrict__ out, int n){
  int i = blockIdx.x*256 + threadIdx.x;
  if (i < n) out[i] = f2bf(in[i]);
}

// WG0 fp32 [103][256] -> bf16 [256][128] (padded, transposed)
__global__ void k_wg0t(const float* __restrict__ WG0, unsigned short* __restrict__ WG0tb){
  int i = blockIdx.x*256 + threadIdx.x;
  if (i >= Hh*KV) return;
  int n = i >> 7, k = i & (KV-1);
  float v = (k < Vv) ? WG0[(size_t)k*Hh + n] : 0.f;
  WG0tb[i] = f2bf(v);
}

// pack [Wih | Whh] -> bf16 [1024][768]
__global__ void k_packW(const float* __restrict__ Wih, const float* __restrict__ Whh,
                        unsigned short* __restrict__ Wp){
  int i = blockIdx.x*256 + threadIdx.x;
  if (i >= 4*Hh*3*Hh) return;
  int g = i / (3*Hh), j = i % (3*Hh);
  float v = (j < 2*Hh) ? Wih[(size_t)g*2*Hh + j] : Whh[(size_t)g*Hh + (j - 2*Hh)];
  Wp[i] = f2bf(v);
}

__global__ void k_count(const int* __restrict__ dst, int* __restrict__ counts){
  int e = blockIdx.x*256 + threadIdx.x;
  if (e < Ee) atomicAdd(&counts[dst[e]], 1);
}

__global__ void k_dinv(const int* __restrict__ counts, float* __restrict__ dinv){
  int n = blockIdx.x*256 + threadIdx.x;
  if (n < Nn) dinv[n] = rsqrtf((float)(counts[n] + 1));
}

// ---------------- hierarchical scan (3 phases) ----------------
__global__ void k_scan1(const int* __restrict__ counts, int* __restrict__ partial){
  __shared__ int red[256];
  int t = threadIdx.x;
  int base = blockIdx.x*SCHUNK + t*4;
  int s = 0;
  if (base + 3 < Nn){ int4 v = *reinterpret_cast<const int4*>(counts + base); s = v.x+v.y+v.z+v.w; }
  else { for (int i=0;i<4;++i) if (base+i<Nn) s += counts[base+i]; }
  red[t] = s; __syncthreads();
  for (int st=128; st>0; st>>=1){ if (t<st) red[t]+=red[t+st]; __syncthreads(); }
  if (t==0) partial[blockIdx.x] = red[0];
}

__global__ void k_scan2(int* __restrict__ partial, int n){
  __shared__ int buf[128];
  int t = threadIdx.x;
  int v = (t < n) ? partial[t] : 0;
  buf[t] = v; __syncthreads();
  for (int off=1; off<128; off<<=1){
    int tv = (t>=off) ? buf[t-off] : 0;
    __syncthreads();
    buf[t] += tv;
    __syncthreads();
  }
  if (t < n) partial[t] = buf[t] - v;
}

__global__ void k_scan3(const int* __restrict__ counts, const int* __restrict__ partial,
                        int* __restrict__ offs){
  __shared__ int red[256];
  int t = threadIdx.x;
  int base = blockIdx.x*SCHUNK + t*4;
  int c0=0,c1=0,c2=0,c3=0;
  if (base + 3 < Nn){ int4 v = *reinterpret_cast<const int4*>(counts + base); c0=v.x;c1=v.y;c2=v.z;c3=v.w; }
  else { if (base<Nn) c0=counts[base]; if (base+1<Nn) c1=counts[base+1];
         if (base+2<Nn) c2=counts[base+2]; if (base+3<Nn) c3=counts[base+3]; }
  int s = c0+c1+c2+c3;
  red[t] = s; __syncthreads();
  for (int off=1; off<256; off<<=1){
    int tv = (t>=off) ? red[t-off] : 0;
    __syncthreads();
    red[t] += tv;
    __syncthreads();
  }
  int run = partial[blockIdx.x] + red[t] - s;
  if (base   < Nn) offs[base]   = run; run += c0;
  if (base+1 < Nn) offs[base+1] = run; run += c1;
  if (base+2 < Nn) offs[base+2] = run; run += c2;
  if (base+3 < Nn) offs[base+3] = run; run += c3;
  if (blockIdx.x == gridDim.x-1 && t == 255) offs[Nn] = partial[blockIdx.x] + red[255];
}

__global__ void k_copyi(const int* __restrict__ a, int* __restrict__ b, int n){
  int i = blockIdx.x*256 + threadIdx.x;
  if (i < n) b[i] = a[i];
}

__global__ void k_fill(const int* __restrict__ ei, const float* __restrict__ dinv,
                       int* __restrict__ fptr, int* __restrict__ srcs, float* __restrict__ norms){
  int e = blockIdx.x*256 + threadIdx.x;
  if (e >= Ee) return;
  int s = ei[e], d = ei[Ee + e];
  int pos = atomicAdd(&fptr[d], 1);
  srcs[pos]  = s;
  norms[pos] = dinv[s]*dinv[d];
}

__global__ void k_boffs(const int* __restrict__ batch, int* __restrict__ boffs){
  int b = blockIdx.x*256 + threadIdx.x;
  if (b > Bb) return;
  int lo = 0, hi = Nn;
  while (lo < hi){ int mid = (lo+hi)>>1; if (batch[mid] < b) lo = mid+1; else hi = mid; }
  boffs[b] = lo;
}

// ---------------- layer 0: vocab histogram (wave per node) ----------------
__global__ void k_hist(const int* __restrict__ sto_x, const int* __restrict__ offs,
                       const int* __restrict__ srcs, const float* __restrict__ norms,
                       const float* __restrict__ dinv, unsigned short* __restrict__ Vb){
  __shared__ float hist[4][KV];
  int wid = threadIdx.x >> 6, lane = threadIdx.x & 63;
  int n = blockIdx.x*4 + wid;
  hist[wid][lane] = 0.f; hist[wid][lane+64] = 0.f;
  __syncthreads();
  int s = offs[n], e = offs[n+1];
  for (int k = s + lane; k < e; k += 64){
    int r2 = sto_x[srcs[k]]; r2 = (r2 == 0) ? (Vv-1) : r2-1;
    atomicAdd(&hist[wid][r2], norms[k]);
  }
  if (lane == 0){
    int r0 = sto_x[n]; r0 = (r0 == 0) ? (Vv-1) : r0-1;
    float dn = dinv[n];
    atomicAdd(&hist[wid][r0], dn*dn);
  }
  __syncthreads();
  unsigned int p = ((unsigned int)f2bf(hist[wid][2*lane+1]) << 16) | f2bf(hist[wid][2*lane]);
  ((unsigned int*)Vb)[(size_t)n*(KV/2) + lane] = p;
}

// ---------------- GCN aggregate (wave per node, uint2 lanes, 4-edge unroll) ----------------
__global__ void k_agg(const unsigned short* __restrict__ Xb, const int* __restrict__ offs,
                      const int* __restrict__ srcs, const float* __restrict__ norms,
                      const float* __restrict__ dinv, unsigned short* __restrict__ T){
  int wid = threadIdx.x >> 6, lane = threadIdx.x & 63;
  int n = blockIdx.x*4 + wid;
  const uint2* Xv = (const uint2*)Xb;
  uint2 v = Xv[(size_t)n*64 + lane];
  float dn = dinv[n]; float s2 = dn*dn;
  float a0 = bf2f(v.x)*s2, a1 = bf2f(v.x>>16)*s2;
  float a2 = bf2f(v.y)*s2, a3 = bf2f(v.y>>16)*s2;
  int s = offs[n], e = offs[n+1];
  int k = s;
  for (; k + 3 < e; k += 4){
    int s0 = srcs[k], s1 = srcs[k+1], s2i = srcs[k+2], s3 = srcs[k+3];
    float n0 = norms[k], n1 = norms[k+1], n2 = norms[k+2], n3 = norms[k+3];
    uint2 g0 = Xv[(size_t)s0*64 + lane];
    uint2 g1 = Xv[(size_t)s1*64 + lane];
    uint2 g2 = Xv[(size_t)s2i*64 + lane];
    uint2 g3 = Xv[(size_t)s3*64 + lane];
    a0 += bf2f(g0.x)*n0; a1 += bf2f(g0.x>>16)*n0; a2 += bf2f(g0.y)*n0; a3 += bf2f(g0.y>>16)*n0;
    a0 += bf2f(g1.x)*n1; a1 += bf2f(g1.x>>16)*n1; a2 += bf2f(g1.y)*n1; a3 += bf2f(g1.y>>16)*n1;
    a0 += bf2f(g2.x)*n2; a1 += bf2f(g2.x>>16)*n2; a2 += bf2f(g2.y)*n2; a3 += bf2f(g2.y>>16)*n2;
    a0 += bf2f(g3.x)*n3; a1 += bf2f(g3.x>>16)*n3; a2 += bf2f(g3.y)*n3; a3 += bf2f(g3.y>>16)*n3;
  }
  for (; k < e; ++k){
    uint2 g0 = Xv[(size_t)srcs[k]*64 + lane];
    float n0 = norms[k];
    a0 += bf2f(g0.x)*n0; a1 += bf2f(g0.x>>16)*n0;
    a2 += bf2f(g0.y)*n0; a3 += bf2f(g0.y>>16)*n0;
  }
  uint2 o;
  o.x = (unsigned int)f2bf(a0) | ((unsigned int)f2bf(a1) << 16);
  o.y = (unsigned int)f2bf(a2) | ((unsigned int)f2bf(a3) << 16);
  ((uint2*)T)[(size_t)n*64 + lane] = o;
}

// ---------------- 8-wave bf16 MFMA NT GEMM, 128x128 tile, coalesced bf16 epilogue ------------
// Block = 512 threads (8 waves), wave tile 32(M) x 64(N), BK=32, 2 barriers/kstep.
// out = epi(A@Bt^T + bias [+ addf]); epi: *rowscale, relu.
// Cf (fp32): direct stores (64B/row segments, no amplification).
// Cb (bf16): wave-local LDS bounce -> short8 row-major stores (128B/row segments).
// Requires: Nc % 128 == 0, K % 32 == 0.
__global__ __launch_bounds__(512) void k_gemm8(
    const unsigned short* __restrict__ A, int lda,
    const unsigned short* __restrict__ Bt,
    const float* __restrict__ bias, const float* __restrict__ rowscale,
    const float* __restrict__ addf,
    float* __restrict__ Cf, unsigned short* __restrict__ Cb,
    int M, int K, int Nc, int relu)
{
  __shared__ unsigned short lds[18432];                 // 36,864 B
  unsigned short (*Al)[40] = (unsigned short(*)[40])lds;            // 128x40
  unsigned short (*Bl)[40] = (unsigned short(*)[40])(lds + 128*40); // 128x40

  int tid = threadIdx.x;
  int w = tid >> 6, lane = tid & 63;
  int wr = (w >> 1)*32, wc = (w & 1)*64;
  int l16 = lane & 15, kh = lane >> 4;
  int rbase = blockIdx.y*128, cbase = blockIdx.x*128;
  int sr = tid >> 2, sb = tid & 3;

  f32x4 acc[2][4] = {};

  for (int k0 = 0; k0 < K; k0 += 32){
    int kk = k0 + sb*8;
    uint4 a0 = make_uint4(0,0,0,0);
    int ar0 = rbase + sr;
    if (ar0 < M) a0 = *reinterpret_cast<const uint4*>(A + (size_t)ar0*lda + kk);
    uint4 b0 = *reinterpret_cast<const uint4*>(Bt + (size_t)(cbase + sr)*K + kk);
    __syncthreads();
    *reinterpret_cast<uint4*>(&Al[sr][sb*8]) = a0;
    *reinterpret_cast<uint4*>(&Bl[sr][sb*8]) = b0;
    __syncthreads();

    short8 af[2], bfv[4];
    #pragma unroll
    for (int m = 0; m < 2; ++m) af[m] = *reinterpret_cast<const short8*>(&Al[wr + m*16 + l16][kh*8]);
    #pragma unroll
    for (int n2 = 0; n2 < 4; ++n2) bfv[n2] = *reinterpret_cast<const short8*>(&Bl[wc + n2*16 + l16][kh*8]);
    #pragma unroll
    for (int m = 0; m < 2; ++m)
      #pragma unroll
      for (int n2 = 0; n2 < 4; ++n2)
        acc[m][n2] = __builtin_amdgcn_mfma_f32_16x16x32_bf16(af[m], bfv[n2], acc[m][n2], 0, 0, 0);
  }

  if (Cf){
    #pragma unroll
    for (int n2 = 0; n2 < 4; ++n2){
      int col = cbase + wc + n2*16 + l16;
      float bv = bias ? bias[col] : 0.f;
      #pragma unroll
      for (int m = 0; m < 2; ++m){
        #pragma unroll
        for (int i = 0; i < 4; ++i){
          int row = rbase + wr + m*16 + kh*4 + i;
          if (row >= M) continue;
          float v = acc[m][n2][i] + bv;
          if (addf) v += addf[(size_t)row*Nc + col];
          if (rowscale) v *= rowscale[row];
          if (relu) v = fmaxf(v, 0.f);
          Cf[(size_t)row*Nc + col] = v;
        }
      }
    }
  }
  if (Cb){
    __syncthreads();                                   // all waves done reading Al/Bl
    unsigned short* eps = lds + w*(32*72);             // wave-local [32][72] region
    #pragma unroll
    for (int n2 = 0; n2 < 4; ++n2){
      int colg = cbase + wc + n2*16 + l16;
      float bv = bias ? bias[colg] : 0.f;
      #pragma unroll
      for (int m = 0; m < 2; ++m){
        #pragma unroll
        for (int i = 0; i < 4; ++i){
          int lrow = m*16 + kh*4 + i;
          int rowg = rbase + wr + lrow;
          float v = acc[m][n2][i] + bv;
          float rs = (rowscale && rowg < M) ? rowscale[rowg] : 1.f;
          v *= rs;
          if (relu) v = fmaxf(v, 0.f);
          eps[lrow*72 + n2*16 + l16] = f2bf(v);
        }
      }
    }
    // wave-local read-back (compiler inserts lgkmcnt for RAW on LDS)
    int c8 = lane & 7;
    #pragma unroll
    for (int rd = 0; rd < 4; ++rd){
      int lrow = rd*8 + (lane >> 3);
      int rowg = rbase + wr + lrow;
      short8 vv = *reinterpret_cast<const short8*>(&eps[lrow*72 + c8*8]);
      if (rowg < M)
        *reinterpret_cast<short8*>(Cb + (size_t)rowg*Nc + cbase + wc + c8*8) = vv;
    }
  }
}

// ---------------- tiled fp32 NT GEMM (small GEMMs) ----------------
__global__ __launch_bounds__(256) void k_gemm_nt(
    const float* __restrict__ A, const float* __restrict__ Bt,
    const float* __restrict__ bias, const float* __restrict__ Dadd,
    float* __restrict__ C, int M, int K, int Nc, int accum, int act)
{
  __shared__ float As[64][20];
  __shared__ float Bs[64][20];
  int tid = threadIdx.x;
  int rbase = blockIdx.y*64, cbase = blockIdx.x*64;
  int ty = tid>>4, tx = tid&15;
  int lr = tid>>2, lq = tid&3;
  float acc[4][4] = {};
  for (int k0 = 0; k0 < K; k0 += 16){
    float4 av = make_float4(0,0,0,0), bv = make_float4(0,0,0,0);
    int kk = k0 + lq*4;
    int ar = rbase + lr;
    if (ar < M && kk < K){
      if (kk + 3 < K) av = *reinterpret_cast<const float4*>(A + (size_t)ar*K + kk);
      else { float t0[4] = {0,0,0,0}; for (int i=0; i<4 && kk+i<K; ++i) t0[i] = A[(size_t)ar*K + kk + i];
             av = make_float4(t0[0],t0[1],t0[2],t0[3]); }
    }
    int br = cbase + lr;
    if (br < Nc && kk < K){
      if (kk + 3 < K) bv = *reinterpret_cast<const float4*>(Bt + (size_t)br*K + kk);
      else { float t0[4] = {0,0,0,0}; for (int i=0; i<4 && kk+i<K; ++i) t0[i] = Bt[(size_t)br*K + kk + i];
             bv = make_float4(t0[0],t0[1],t0[2],t0[3]); }
    }
    __syncthreads();
    *reinterpret_cast<float4*>(&As[lr][lq*4]) = av;
    *reinterpret_cast<float4*>(&Bs[lr][lq*4]) = bv;
    __syncthreads();
    #pragma unroll
    for (int kc = 0; kc < 16; kc += 4){
      float4 a4[4], b4[4];
      #pragma unroll
      for (int i=0;i<4;++i) a4[i] = *reinterpret_cast<float4*>(&As[ty*4+i][kc]);
      #pragma unroll
      for (int j=0;j<4;++j) b4[j] = *reinterpret_cast<float4*>(&Bs[tx*4+j][kc]);
      #pragma unroll
      for (int i=0;i<4;++i)
        #pragma unroll
        for (int j=0;j<4;++j)
          acc[i][j] += a4[i].x*b4[j].x + a4[i].y*b4[j].y + a4[i].z*b4[j].z + a4[i].w*b4[j].w;
    }
  }
  #pragma unroll
  for (int i=0;i<4;++i){
    int r = rbase + ty*4 + i;
    if (r >= M) continue;
    #pragma unroll
    for (int j=0;j<4;++j){
      int cc = cbase + tx*4 + j;
      if (cc >= Nc) continue;
      float v = acc[i][j];
      if (accum) v += C[(size_t)r*Nc + cc];
      if (bias)  v += bias[cc];
      if (Dadd)  v += Dadd[(size_t)r*Nc + cc];
      if (act == 1) v = (v > 0.f) ? v : 0.01f*v;
      C[(size_t)r*Nc + cc] = v;
    }
  }
}

// ---------------- pooling / LSTM / head ----------------
__global__ void k_bsum(const float* __restrict__ bih, const float* __restrict__ bhh,
                       float* __restrict__ bsum){
  int g = blockIdx.x*256 + threadIdx.x;
  if (g < 4*Hh) bsum[g] = bih[g] + bhh[g];
}

__global__ void k_lstm(const float* __restrict__ gates, float* __restrict__ cbuf,
                       float* __restrict__ hbuf, unsigned short* __restrict__ qh){
  int idx = blockIdx.x*256 + threadIdx.x;
  if (idx >= Bb*Hh) return;
  int b = idx >> 8, ch = idx & 255;
  const float* g = gates + (size_t)b*4*Hh;
  float ig = sigf(g[ch]);
  float fg = sigf(g[Hh + ch]);
  float gg = tanhf(g[2*Hh + ch]);
  float og = sigf(g[3*Hh + ch]);
  float cn = fg*cbuf[idx] + ig*gg;
  float hn = og*tanhf(cn);
  cbuf[idx] = cn; hbuf[idx] = hn;
  unsigned short hb = f2bf(hn);
  qh[(size_t)b*3*Hh + ch] = hb;
  qh[(size_t)b*3*Hh + 2*Hh + ch] = hb;
}

// fused Set2Set pool: wave per graph, online softmax + optional plain-sum (sto)
__global__ void k_pool(const unsigned short* __restrict__ wxb,
                       const float* __restrict__ hbuf,
                       const int* __restrict__ boffs,
                       unsigned short* __restrict__ qh,
                       float* __restrict__ sto, int do_sto){
  int wid = threadIdx.x >> 6, lane = threadIdx.x & 63;
  int g = blockIdx.x*4 + wid;
  if (g >= Bb) return;
  const uint2* Xv = (const uint2*)wxb;
  float4 hv = ((const float4*)hbuf)[(size_t)g*64 + lane];
  int s = boffs[g], e = boffs[g+1];
  float m = -INFINITY, ssum = 0.f;
  float a0=0.f,a1=0.f,a2=0.f,a3=0.f;
  float t0=0.f,t1=0.f,t2=0.f,t3=0.f;
  for (int n = s; n < e; ++n){
    uint2 v = Xv[(size_t)n*64 + lane];
    float x0=bf2f(v.x), x1=bf2f(v.x>>16), x2=bf2f(v.y), x3=bf2f(v.y>>16);
    if (do_sto){ t0+=x0; t1+=x1; t2+=x2; t3+=x3; }
    float d = x0*hv.x + x1*hv.y + x2*hv.z + x3*hv.w;
    #pragma unroll
    for (int mask=32; mask; mask>>=1) d += __shfl_xor(d, mask, 64);
    if (d > m){
      float sc = expf(m - d);
      ssum = ssum*sc + 1.f;
      a0 = a0*sc + x0; a1 = a1*sc + x1; a2 = a2*sc + x2; a3 = a3*sc + x3;
      m = d;
    } else {
      float p = expf(d - m);
      ssum += p;
      a0 += p*x0; a1 += p*x1; a2 += p*x2; a3 += p*x3;
    }
  }
  float inv = 1.f/(ssum + 1e-16f);
  uint2 o;
  o.x = (unsigned int)f2bf(a0*inv) | ((unsigned int)f2bf(a1*inv) << 16);
  o.y = (unsigned int)f2bf(a2*inv) | ((unsigned int)f2bf(a3*inv) << 16);
  ((uint2*)(qh + (size_t)g*3*Hh + Hh))[lane] = o;
  if (do_sto) ((float4*)sto)[(size_t)g*64 + lane] = make_float4(t0,t1,t2,t3);
}

__global__ void k_norm(float* __restrict__ mean){
  __shared__ float red[256];
  int b = blockIdx.x, tid = threadIdx.x;
  float v = mean[(size_t)b*Hh + tid];
  red[tid] = v*v; __syncthreads();
  for (int st=128; st>0; st>>=1){ if (tid<st) red[tid] += red[tid+st]; __syncthreads(); }
  float nrm = fmaxf(sqrtf(red[0]), 1e-12f);
  mean[(size_t)b*Hh + tid] = v/nrm;
}

__global__ void k_out(const float* __restrict__ y1, const float* __restrict__ p2W,
                      const float* __restrict__ p2b, float* __restrict__ out){
  __shared__ float red[128];
  int b = blockIdx.x, tid = threadIdx.x;
  float v = y1[(size_t)b*128 + tid]*p2W[tid];
  red[tid] = v; __syncthreads();
  for (int st=64; st>0; st>>=1){ if (tid<st) red[tid] += red[tid+st]; __syncthreads(); }
  if (tid == 0) out[b] = red[0] + p2b[0];
}

// ---------------- launch ----------------
extern "C" void kernel_launch(void* const* d_in, const int* in_sizes, int n_in,
                              void* d_out, int out_size, void* d_ws, size_t ws_size,
                              hipStream_t stream) {
  const float* weight   = (const float*)d_in[0];
  const int*   sto_x    = (const int*)  d_in[1];
  const int*   ei       = (const int*)  d_in[2];
  const float* sto_w    = (const float*)d_in[3];
  const int*   batch    = (const int*)  d_in[4];
  const float* gW0 = (const float*)d_in[5];   const float* gb0 = (const float*)d_in[6];
  const float* gW1 = (const float*)d_in[7];   const float* gb1 = (const float*)d_in[8];
  const float* gW2 = (const float*)d_in[9];   const float* gb2 = (const float*)d_in[10];
  const float* Wih = (const float*)d_in[11];  const float* Whh = (const float*)d_in[12];
  const float* bih = (const float*)d_in[13];  const float* bhh = (const float*)d_in[14];
  const float* mW  = (const float*)d_in[15];  const float* mb  = (const float*)d_in[16];
  const float* p0W = (const float*)d_in[17];  const float* p0b = (const float*)d_in[18];
  const float* p1W = (const float*)d_in[19];  const float* p1b = (const float*)d_in[20];
  const float* p2W = (const float*)d_in[21];  const float* p2b = (const float*)d_in[22];
  float* out = (float*)d_out;

  // workspace carve (256B aligned)
  char* w = (char*)d_ws;
  auto alloc = [&](size_t bytes)->char*{ char* p = w; w += (bytes + 255) & ~size_t(255); return p; };
  unsigned short* Xb = (unsigned short*)alloc((size_t)Nn*Hh*2);
  unsigned short* Tb = (unsigned short*)alloc((size_t)Nn*Hh*2);
  unsigned short* Vb = (unsigned short*)alloc((size_t)Nn*KV*2);
  float* WG0   = (float*)alloc((size_t)Vv*Hh*4);
  unsigned short* WG0tb = (unsigned short*)alloc((size_t)Hh*KV*2);
  float* gW0t  = (float*)alloc((size_t)Hh*DIN*4);
  unsigned short* gW1tb = (unsigned short*)alloc((size_t)Hh*Hh*2);
  unsigned short* gW2tb = (unsigned short*)alloc((size_t)Hh*Hh*2);
  unsigned short* Wpb   = (unsigned short*)alloc((size_t)4*Hh*3*Hh*2);
  unsigned short* mWb   = (unsigned short*)alloc((size_t)Hh*2*Hh*2);
  int*   counts= (int*)  alloc((size_t)Nn*4);
  int*   offs  = (int*)  alloc((size_t)(Nn+1)*4);
  int*   fptr  = (int*)  alloc((size_t)Nn*4);
  int*   spart = (int*)  alloc((size_t)NSCAN*4);
  float* dinv  = (float*)alloc((size_t)Nn*4);
  int*   srcs  = (int*)  alloc((size_t)Ee*4);
  float* norms = (float*)alloc((size_t)Ee*4);
  int*   boffs = (int*)  alloc((size_t)(Bb+1)*4);
  float* sto   = (float*)alloc((size_t)Bb*Hh*4);
  float* hbuf  = (float*)alloc((size_t)Bb*Hh*4);
  float* cbuf  = (float*)alloc((size_t)Bb*Hh*4);
  unsigned short* qh = (unsigned short*)alloc((size_t)Bb*3*Hh*2);
  float* gates = (float*)alloc((size_t)Bb*4*Hh*4);
  float* bsum  = (float*)alloc((size_t)4*Hh*4);
  float* meanb = (float*)alloc((size_t)Bb*Hh*4);
  float* y0    = (float*)alloc((size_t)Bb*128*4);
  float* y1    = (float*)alloc((size_t)Bb*128*4);

  auto gemm = [&](const float* A, const float* Bt, const float* bias, const float* Dadd,
                  float* C, int M, int K, int Nc, int accum, int act){
    dim3 g((Nc+63)/64, (M+63)/64);
    k_gemm_nt<<<g, 256, 0, stream>>>(A, Bt, bias, Dadd, C, M, K, Nc, accum, act);
  };
  auto gemm8 = [&](const unsigned short* A, int lda, const unsigned short* Bt,
                   const float* bias, const float* rowscale, const float* addf,
                   float* Cf, unsigned short* Cb, int M, int K, int Nc, int relu){
    dim3 g(Nc/128, (M+127)/128);
    k_gemm8<<<g, 512, 0, stream>>>(A, lda, Bt, bias, rowscale, addf, Cf, Cb, M, K, Nc, relu);
  };

  // per-launch state init (deterministic every call)
  hipMemsetAsync(counts, 0, (size_t)Nn*4, stream);
  hipMemsetAsync(cbuf,  0, (size_t)Bb*Hh*4, stream);
  hipMemsetAsync(qh,    0, (size_t)Bb*3*Hh*2, stream);

  // weight prep
  k_transpose<<<(DIN*Hh+255)/256, 256, 0, stream>>>(gW0, gW0t, DIN, Hh);
  k_transpose_b<<<(Hh*Hh+255)/256, 256, 0, stream>>>(gW1, gW1tb, Hh, Hh);
  k_transpose_b<<<(Hh*Hh+255)/256, 256, 0, stream>>>(gW2, gW2tb, Hh, Hh);
  k_packW<<<(4*Hh*3*Hh+255)/256, 256, 0, stream>>>(Wih, Whh, Wpb);
  k_castb<<<(Hh*2*Hh+255)/256, 256, 0, stream>>>(mW, mWb, Hh*2*Hh);

  // graph structure (hierarchical scan)
  k_count<<<(Ee+255)/256, 256, 0, stream>>>(ei + Ee, counts);
  k_dinv<<<(Nn+255)/256, 256, 0, stream>>>(counts, dinv);
  k_scan1<<<NSCAN, 256, 0, stream>>>(counts, spart);
  k_scan2<<<1, 128, 0, stream>>>(spart, NSCAN);
  k_scan3<<<NSCAN, 256, 0, stream>>>(counts, spart, offs);
  k_copyi<<<(Nn+255)/256, 256, 0, stream>>>(offs, fptr, Nn);
  k_fill<<<(Ee+255)/256, 256, 0, stream>>>(ei, dinv, fptr, srcs, norms);
  k_boffs<<<(Bb+256)/256, 256, 0, stream>>>(batch, boffs);

  // layer 0: WG0 = weight@gW0, vocab histogram, GEMM (bias+relu)
  gemm(weight, gW0t, nullptr, nullptr, WG0, Vv, DIN, Hh, 0, 0);
  k_wg0t<<<(Hh*KV+255)/256, 256, 0, stream>>>(WG0, WG0tb);
  k_hist<<<Nn/4, 256, 0, stream>>>(sto_x, offs, srcs, norms, dinv, Vb);
  gemm8(Vb, KV, WG0tb, gb0, nullptr, nullptr, nullptr, Xb, Nn, KV, Hh, 1);

  // layers 1,2: aggregate-first, GEMM with fused epilogue
  k_agg<<<Nn/4, 256, 0, stream>>>(Xb, offs, srcs, norms, dinv, Tb);
  gemm8(Tb, Hh, gW1tb, gb1, nullptr, nullptr, nullptr, Xb, Nn, Hh, Hh, 1);
  k_agg<<<Nn/4, 256, 0, stream>>>(Xb, offs, srcs, norms, dinv, Tb);
  gemm8(Tb, Hh, gW2tb, gb2, sto_w, nullptr, nullptr, Xb, Nn, Hh, Hh, 0);  // Xb = wx

  k_bsum<<<(4*Hh+255)/256, 256, 0, stream>>>(bih, bhh, bsum);

  // Set2Set (2 steps): gates GEMM, LSTM, fused pool (sto accumulated at t=0)
  for (int t = 0; t < 2; ++t){
    gemm8(qh, 3*Hh, Wpb, bsum, nullptr, nullptr, gates, nullptr, Bb, 3*Hh, 4*Hh, 0);
    k_lstm<<<(Bb*Hh+255)/256, 256, 0, stream>>>(gates, cbuf, hbuf, qh);
    k_pool<<<Bb/4, 256, 0, stream>>>(Xb, hbuf, boffs, qh, sto, t == 0);
  }

  // head
  gemm8(qh, 3*Hh, mWb, mb, nullptr, sto, meanb, nullptr, Bb, 2*Hh, Hh, 0);
  k_norm<<<Bb, Hh, 0, stream>>>(meanb);
  gemm(meanb, p0W, p0b, nullptr, y0, Bb, Hh, 128, 0, 1);
  gemm(y0, p1W, p1b, nullptr, y1, Bb, 128, 128, 0, 1);
  k_out<<<Bb, 128, 0, stream>>>(y1, p2W, p2b, out);
}